// Round 7
// baseline (270.698 us; speedup 1.0000x reference)
//
#include <hip/hip_runtime.h>

#define DIM 128
#define CAP 48

typedef _Float16 half8 __attribute__((ext_vector_type(8)));
typedef float f32x4 __attribute__((ext_vector_type(4)));

__device__ __forceinline__ float lrelu(float v) { return v > 0.f ? v : 0.01f * v; }

// ---------------- prep: CSR-lite fill + pack W1/W2 to B-frag order + x -> fp16 ----------------
// blocks [0,eb): fill; [eb,eb+64): pack W1; [eb+64,eb+192): pack W2; rest: convert x
__global__ __launch_bounds__(256) void k_prep(
    const int* __restrict__ src, const int* __restrict__ dst,
    int* __restrict__ cursor, int* __restrict__ srcs, int e, int eb,
    const float* __restrict__ W1, _Float16* __restrict__ Wp1,
    const float* __restrict__ W2, _Float16* __restrict__ Wp2,
    const float* __restrict__ x, _Float16* __restrict__ xh, long long nx) {
    int b = blockIdx.x;
    if (b < eb) {
        int i = b * 256 + threadIdx.x;
        if (i < e) {
            int d = dst[i];
            int p = atomicAdd(&cursor[d], 1);
            if (p < CAP) srcs[(size_t)d * CAP + p] = src[i];
        }
        return;
    }
    b -= eb;
    if (b < 192) {
        const float* W;
        _Float16* Wp;
        int tid2;
        if (b < 64) { W = W1; Wp = Wp1; tid2 = b * 256 + threadIdx.x; }
        else        { W = W2; Wp = Wp2; tid2 = (b - 64) * 256 + threadIdx.x; }
        // frag (kb,cb): lane l elem j holds W[k=kb*32+(l>>4)*8+j][n=cb*16+(l&15)]
        int jj = tid2 & 7;
        int frag = tid2 >> 3;
        int l = frag & 63;
        int cb = (frag >> 6) & 7;
        int kb = frag >> 9;
        int k = kb * 32 + ((l >> 4) << 3) + jj;
        int nn = cb * 16 + (l & 15);
        Wp[tid2] = (_Float16)W[(size_t)k * DIM + nn];
        return;
    }
    b -= 192;
    long long i0 = ((long long)b * 256 + threadIdx.x) * 8;
    if (i0 < nx) {
        float4 v0 = *(const float4*)&x[i0];
        float4 v1 = *(const float4*)&x[i0 + 4];
        half8 o;
        o[0] = (_Float16)v0.x; o[1] = (_Float16)v0.y;
        o[2] = (_Float16)v0.z; o[3] = (_Float16)v0.w;
        o[4] = (_Float16)v1.x; o[5] = (_Float16)v1.y;
        o[6] = (_Float16)v1.z; o[7] = (_Float16)v1.w;
        *(half8*)&xh[i0] = o;
    }
}

// ---------------- mm1 (fused dual-GEMM, 64-row tiles) ----------------
// hs = f16((x@W1)*dinv)  (row-major, coalesced via LDS transpose)
// P  = f16(lrelu(x)@W2[0:128,:])  (acc-image, block-private)
__global__ __launch_bounds__(256, 2) void k_mm1(
    const _Float16* __restrict__ xh, const _Float16* __restrict__ Wp1,
    const _Float16* __restrict__ Wp2, const int* __restrict__ cursor,
    _Float16* __restrict__ hs, _Float16* __restrict__ P, int n) {
    __shared__ _Float16 Hs[64 * 136];
    const int tid = threadIdx.x;
    const int w = tid >> 6, l = tid & 63;
    const int row0 = blockIdx.x * 64;
    const int arow = row0 + w * 16 + (l & 15);
    const int kq = (l >> 4) << 3;
    const bool ok = arow < n;
    const _Float16* xr = &xh[(size_t)arow * DIM + kq];

    f32x4 ah[8], ap[8];
#pragma unroll
    for (int cb = 0; cb < 8; ++cb) {
        f32x4 z = {0.f, 0.f, 0.f, 0.f};
        ah[cb] = z; ap[cb] = z;
    }

#pragma unroll
    for (int kb = 0; kb < 4; ++kb) {
        half8 a = 0;
        if (ok) a = *(const half8*)&xr[kb * 32];
        half8 al;
#pragma unroll
        for (int e = 0; e < 8; ++e) {
            _Float16 t = a[e];
            al[e] = (t > (_Float16)0.f) ? t : t * (_Float16)0.01f;
        }
#pragma unroll
        for (int cb = 0; cb < 8; ++cb) {
            half8 bf = *(const half8*)&Wp1[((kb * 8 + cb) * 64 + l) * 8];
            ah[cb] = __builtin_amdgcn_mfma_f32_16x16x32_f16(a, bf, ah[cb], 0, 0, 0);
        }
#pragma unroll
        for (int cb = 0; cb < 8; ++cb) {
            half8 bf = *(const half8*)&Wp2[((kb * 8 + cb) * 64 + l) * 8];  // W2 rows 0..127
            ap[cb] = __builtin_amdgcn_mfma_f32_16x16x32_f16(al, bf, ap[cb], 0, 0, 0);
        }
    }
    // hs: accs -> LDS (scaled) -> coalesced stores
    const int orow = w * 16 + ((l >> 4) << 2);
    const int oc = l & 15;
#pragma unroll
    for (int reg = 0; reg < 4; ++reg) {
        int grow = row0 + orow + reg;
        float d = (grow < n) ? rsqrtf((float)cursor[grow] + 1.0f) : 0.f;
#pragma unroll
        for (int cb = 0; cb < 8; ++cb)
            Hs[(orow + reg) * 136 + cb * 16 + oc] = (_Float16)(ah[cb][reg] * d);
    }
    __syncthreads();
#pragma unroll
    for (int it = 0; it < 4; ++it) {
        int i = it * 256 + tid;          // 1024 chunks of 8 halfs
        int r = i >> 4, c = (i & 15) * 8;
        if (row0 + r < n)
            *(half8*)&hs[(size_t)(row0 + r) * DIM + c] = *(const half8*)&Hs[r * 136 + c];
    }
    // P: acc-image, 32 halfs/lane contiguous
    _Float16* pl = P + ((size_t)(blockIdx.x * 4 + w) * 64 + l) * 32;
#pragma unroll
    for (int c = 0; c < 4; ++c) {
        half8 o;
#pragma unroll
        for (int e = 0; e < 4; ++e) {
            o[e]     = (_Float16)ap[2 * c][e];
            o[4 + e] = (_Float16)ap[2 * c + 1][e];
        }
        *(half8*)&pl[c * 8] = o;
    }
}

// ---------------- mm2g: fused gather1 + GEMM2-half ----------------
// wave-per-node gather (4 edges in flight), frag-order LDS A-tile, MFMA, LDS-transpose epilogue.
// hs2 aliases P (block-private; P fully consumed before first barrier).
__global__ __launch_bounds__(256, 2) void k_mm2g(
    const _Float16* __restrict__ hs, const int* __restrict__ cursor,
    const int* __restrict__ srcs, const float* __restrict__ b1,
    const _Float16* __restrict__ Wp2, const _Float16* __restrict__ P,
    _Float16* __restrict__ hs2, int n) {
    __shared__ _Float16 LS[64 * 136];  // Af (first 8192) then Hs
    const int tid = threadIdx.x;
    const int w = tid >> 6, l = tid & 63;
    const int g = l & 15, eq = l >> 4;
    const int row0 = blockIdx.x * 64;

    // init acc from P
    f32x4 acc[8];
    const _Float16* pl = P + ((size_t)(blockIdx.x * 4 + w) * 64 + l) * 32;
#pragma unroll
    for (int c = 0; c < 4; ++c) {
        half8 pv = *(const half8*)&pl[c * 8];
#pragma unroll
        for (int e = 0; e < 4; ++e) {
            acc[2 * c][e]     = (float)pv[e];
            acc[2 * c + 1][e] = (float)pv[4 + e];
        }
    }

    // gather: wave w handles nodes row0 + w*16 + s
    for (int s = 0; s < 16; ++s) {
        int node = row0 + w * 16 + s;
        if (node < n) {
            int rawc = cursor[node];
            int cnt = rawc > CAP ? CAP : rawc;
            int sidall = (l < cnt) ? srcs[(size_t)node * CAP + l] : 0;
            half8 h = *(const half8*)&hs[(size_t)node * DIM + g * 8];
            float a[8];
            // self term ONCE: only eq==0 lanes seed with h (xor-reduce sums the 4 eq lanes)
#pragma unroll
            for (int e = 0; e < 8; ++e) a[e] = (eq == 0) ? (float)h[e] : 0.f;
            int iters = (cnt + 3) >> 2;
            for (int t = 0; t < iters; ++t) {
                int idx = t * 4 + eq;
                int sj = __shfl(sidall, idx, 64);
                if (idx < cnt) {
                    half8 v = *(const half8*)&hs[(size_t)sj * DIM + g * 8];
#pragma unroll
                    for (int e = 0; e < 8; ++e) a[e] += (float)v[e];
                }
            }
#pragma unroll
            for (int e = 0; e < 8; ++e) {
                a[e] += __shfl_xor(a[e], 16, 64);
                a[e] += __shfl_xor(a[e], 32, 64);
            }
            if (eq == 0) {
                float d = rsqrtf((float)rawc + 1.0f);
                const float4 bb0 = *(const float4*)&b1[g * 8];
                const float4 bb1 = *(const float4*)&b1[g * 8 + 4];
                half8 o;
                o[0] = (_Float16)lrelu(fmaf(a[0], d, bb0.x));
                o[1] = (_Float16)lrelu(fmaf(a[1], d, bb0.y));
                o[2] = (_Float16)lrelu(fmaf(a[2], d, bb0.z));
                o[3] = (_Float16)lrelu(fmaf(a[3], d, bb0.w));
                o[4] = (_Float16)lrelu(fmaf(a[4], d, bb1.x));
                o[5] = (_Float16)lrelu(fmaf(a[5], d, bb1.y));
                o[6] = (_Float16)lrelu(fmaf(a[6], d, bb1.z));
                o[7] = (_Float16)lrelu(fmaf(a[7], d, bb1.w));
                // frag write: frag = w*4 + (g>>2), lane-in-frag = (g&3)*16 + s
                *(half8*)&LS[(((w * 4 + (g >> 2)) * 64) + (g & 3) * 16 + s) * 8] = o;
            }
        }
    }
    // each wave reads only frags it wrote -> in-wave LDS ordering, no barrier needed
#pragma unroll
    for (int kb = 0; kb < 4; ++kb) {
        half8 a = *(const half8*)&LS[((w * 4 + kb) * 64 + l) * 8];
#pragma unroll
        for (int cb = 0; cb < 8; ++cb) {
            half8 bf = *(const half8*)&Wp2[(((kb + 4) * 8 + cb) * 64 + l) * 8];  // W2 rows 128..255
            acc[cb] = __builtin_amdgcn_mfma_f32_16x16x32_f16(a, bf, acc[cb], 0, 0, 0);
        }
    }
    __syncthreads();  // all waves done with Af before Hs overwrite
    const int orow = w * 16 + ((l >> 4) << 2);
    const int oc = l & 15;
#pragma unroll
    for (int reg = 0; reg < 4; ++reg) {
        int grow = row0 + orow + reg;
        float d = (grow < n) ? rsqrtf((float)cursor[grow] + 1.0f) : 0.f;
#pragma unroll
        for (int cb = 0; cb < 8; ++cb)
            LS[(orow + reg) * 136 + cb * 16 + oc] = (_Float16)(acc[cb][reg] * d);
    }
    __syncthreads();
#pragma unroll
    for (int it = 0; it < 4; ++it) {
        int i = it * 256 + tid;
        int r = i >> 4, c = (i & 15) * 8;
        if (row0 + r < n)
            *(half8*)&hs2[(size_t)(row0 + r) * DIM + c] = *(const half8*)&LS[r * 136 + c];
    }
}

// ---------------- gather2 + final projection (wave per node) ----------------
__global__ __launch_bounds__(256) void k_gather2(
    const _Float16* __restrict__ hs2, const int* __restrict__ cursor,
    const int* __restrict__ srcs, const float* __restrict__ b2,
    const float* __restrict__ wout, const float* __restrict__ bout,
    float* __restrict__ out, int n) {
    const int w = threadIdx.x >> 6, l = threadIdx.x & 63;
    const int g = l & 15, eq = l >> 4;
    const int node = blockIdx.x * 4 + w;
    if (node >= n) return;
    int rawc = cursor[node];
    int cnt = rawc > CAP ? CAP : rawc;
    int sidall = (l < cnt) ? srcs[(size_t)node * CAP + l] : 0;
    half8 h = *(const half8*)&hs2[(size_t)node * DIM + g * 8];
    float a[8];
    // self term ONCE: only eq==0 lanes seed with h
#pragma unroll
    for (int e = 0; e < 8; ++e) a[e] = (eq == 0) ? (float)h[e] : 0.f;
    int iters = (cnt + 3) >> 2;
    for (int t = 0; t < iters; ++t) {
        int idx = t * 4 + eq;
        int sj = __shfl(sidall, idx, 64);
        if (idx < cnt) {
            half8 v = *(const half8*)&hs2[(size_t)sj * DIM + g * 8];
#pragma unroll
            for (int e = 0; e < 8; ++e) a[e] += (float)v[e];
        }
    }
#pragma unroll
    for (int e = 0; e < 8; ++e) {
        a[e] += __shfl_xor(a[e], 16, 64);
        a[e] += __shfl_xor(a[e], 32, 64);
    }
    if (eq == 0) {
        float d = rsqrtf((float)rawc + 1.0f);
        const float4 bb0 = *(const float4*)&b2[g * 8];
        const float4 bb1 = *(const float4*)&b2[g * 8 + 4];
        const float4 wv0 = *(const float4*)&wout[g * 8];
        const float4 wv1 = *(const float4*)&wout[g * 8 + 4];
        float s = lrelu(fmaf(a[0], d, bb0.x)) * wv0.x + lrelu(fmaf(a[1], d, bb0.y)) * wv0.y +
                  lrelu(fmaf(a[2], d, bb0.z)) * wv0.z + lrelu(fmaf(a[3], d, bb0.w)) * wv0.w +
                  lrelu(fmaf(a[4], d, bb1.x)) * wv1.x + lrelu(fmaf(a[5], d, bb1.y)) * wv1.y +
                  lrelu(fmaf(a[6], d, bb1.z)) * wv1.z + lrelu(fmaf(a[7], d, bb1.w)) * wv1.w;
#pragma unroll
        for (int off = 8; off > 0; off >>= 1) s += __shfl_down(s, off, 16);
        if (g == 0) out[node] = s + bout[0];
    }
}

extern "C" void kernel_launch(void* const* d_in, const int* in_sizes, int n_in,
                              void* d_out, int out_size, void* d_ws, size_t ws_size,
                              hipStream_t stream) {
    const float* x    = (const float*)d_in[0];
    const int*   ei   = (const int*)d_in[1];
    const float* W1   = (const float*)d_in[2];
    const float* b1   = (const float*)d_in[3];
    const float* W2   = (const float*)d_in[4];
    const float* b2   = (const float*)d_in[5];
    const float* Wout = (const float*)d_in[6];
    const float* bout = (const float*)d_in[7];
    float* out = (float*)d_out;

    const int N = in_sizes[0] / DIM;
    const int E = in_sizes[1] / 2;
    const int* src = ei;      // edge_index[0]
    const int* dst = ei + E;  // edge_index[1]

    const int gb = (N + 63) / 64;
    const long long nx = (long long)N * DIM;

    // workspace
    size_t Na = ((size_t)N + 63) & ~(size_t)63;
    int* cursor   = (int*)d_ws;                          // Na
    int* srcs     = cursor + Na;                         // N*CAP
    _Float16* Wp1 = (_Float16*)(srcs + (size_t)N * CAP); // 128*128
    _Float16* Wp2 = Wp1 + 128 * 128;                     // 256*128
    _Float16* xhb = Wp2 + 256 * 128;                     // N*128 (fp16 x)
    _Float16* hsb = xhb + nx;                            // N*128 (hs)
    _Float16* Pb  = hsb + nx;                            // gb*8192 (P -> hs2)

    const int eb = (E + 255) / 256;
    const int cvb = (int)((nx + 2047) / 2048);

    hipMemsetAsync(cursor, 0, (size_t)N * sizeof(int), stream);
    k_prep<<<eb + 192 + cvb, 256, 0, stream>>>(src, dst, cursor, srcs, E, eb,
                                               W1, Wp1, W2, Wp2, x, xhb, nx);
    k_mm1<<<gb, 256, 0, stream>>>(xhb, Wp1, Wp2, cursor, hsb, Pb, N);
    k_mm2g<<<gb, 256, 0, stream>>>(hsb, cursor, srcs, b1, Wp2, Pb, Pb, N);
    k_gather2<<<(N + 3) / 4, 256, 0, stream>>>(Pb, cursor, srcs, b2, Wout, bout, out, N);
}

// Round 8
// 230.152 us; speedup vs baseline: 1.1762x; 1.1762x over previous
//
#include <hip/hip_runtime.h>

#define DIM 128
#define CAP 48

typedef _Float16 half8 __attribute__((ext_vector_type(8)));
typedef float f32x4 __attribute__((ext_vector_type(4)));

__device__ __forceinline__ float lrelu(float v) { return v > 0.f ? v : 0.01f * v; }

// ---------------- prep: CSR-lite fill + pack W1/W2 to MFMA B-frag order ----------------
// blocks [0,eb): edge fill; [eb,eb+64): pack W1; [eb+64,eb+192): pack W2
__global__ __launch_bounds__(256) void k_prep(
    const int* __restrict__ src, const int* __restrict__ dst,
    int* __restrict__ cursor, int* __restrict__ srcs, int e, int eb,
    const float* __restrict__ W1, _Float16* __restrict__ Wp1,
    const float* __restrict__ W2, _Float16* __restrict__ Wp2) {
    int b = blockIdx.x;
    if (b < eb) {
        int i = b * 256 + threadIdx.x;
        if (i < e) {
            int d = dst[i];
            int p = atomicAdd(&cursor[d], 1);
            if (p < CAP) srcs[(size_t)d * CAP + p] = src[i];
        }
        return;
    }
    b -= eb;
    const float* W;
    _Float16* Wp;
    int tid2;
    if (b < 64) { W = W1; Wp = Wp1; tid2 = b * 256 + threadIdx.x; }
    else        { W = W2; Wp = Wp2; tid2 = (b - 64) * 256 + threadIdx.x; }
    // frag (kb,cb): lane l elem j holds W[k=kb*32+(l>>4)*8+j][n=cb*16+(l&15)]
    int jj = tid2 & 7;
    int frag = tid2 >> 3;
    int l = frag & 63;
    int cb = (frag >> 6) & 7;
    int kb = frag >> 9;
    int k = kb * 32 + ((l >> 4) << 3) + jj;
    int nn = cb * 16 + (l & 15);
    Wp[tid2] = (_Float16)W[(size_t)k * DIM + nn];
}

// ---------------- mm1 (fused dual-GEMM, 64-row tiles, fp32 x direct) ----------------
// hs = f16((x@W1)*dinv)  (row-major, coalesced via LDS transpose)
// P  = f16(lrelu(x)@W2[0:128,:])  (acc-image, block-private)
__global__ __launch_bounds__(256, 2) void k_mm1(
    const float* __restrict__ x, const _Float16* __restrict__ Wp1,
    const _Float16* __restrict__ Wp2, const int* __restrict__ cursor,
    _Float16* __restrict__ hs, _Float16* __restrict__ P, int n) {
    __shared__ _Float16 Hs[64 * 136];
    const int tid = threadIdx.x;
    const int w = tid >> 6, l = tid & 63;
    const int row0 = blockIdx.x * 64;
    const int arow = row0 + w * 16 + (l & 15);
    const int kq = (l >> 4) << 3;
    const bool ok = arow < n;
    const float* xr = &x[(size_t)arow * DIM + kq];

    f32x4 ah[8], ap[8];
#pragma unroll
    for (int cb = 0; cb < 8; ++cb) {
        f32x4 z = {0.f, 0.f, 0.f, 0.f};
        ah[cb] = z; ap[cb] = z;
    }

#pragma unroll
    for (int kb = 0; kb < 4; ++kb) {
        float4 v0 = make_float4(0.f, 0.f, 0.f, 0.f), v1 = v0;
        if (ok) {
            v0 = *(const float4*)&xr[kb * 32];
            v1 = *(const float4*)&xr[kb * 32 + 4];
        }
        half8 a, al;
        a[0] = (_Float16)v0.x; a[1] = (_Float16)v0.y;
        a[2] = (_Float16)v0.z; a[3] = (_Float16)v0.w;
        a[4] = (_Float16)v1.x; a[5] = (_Float16)v1.y;
        a[6] = (_Float16)v1.z; a[7] = (_Float16)v1.w;
#pragma unroll
        for (int e = 0; e < 8; ++e) {
            _Float16 t = a[e];
            al[e] = (t > (_Float16)0.f) ? t : t * (_Float16)0.01f;
        }
#pragma unroll
        for (int cb = 0; cb < 8; ++cb) {
            half8 bf = *(const half8*)&Wp1[((kb * 8 + cb) * 64 + l) * 8];
            ah[cb] = __builtin_amdgcn_mfma_f32_16x16x32_f16(a, bf, ah[cb], 0, 0, 0);
        }
#pragma unroll
        for (int cb = 0; cb < 8; ++cb) {
            half8 bf = *(const half8*)&Wp2[((kb * 8 + cb) * 64 + l) * 8];  // W2 rows 0..127
            ap[cb] = __builtin_amdgcn_mfma_f32_16x16x32_f16(al, bf, ap[cb], 0, 0, 0);
        }
    }
    // hs: accs -> LDS (scaled) -> coalesced stores
    const int orow = w * 16 + ((l >> 4) << 2);
    const int oc = l & 15;
#pragma unroll
    for (int reg = 0; reg < 4; ++reg) {
        int grow = row0 + orow + reg;
        float d = (grow < n) ? rsqrtf((float)cursor[grow] + 1.0f) : 0.f;
#pragma unroll
        for (int cb = 0; cb < 8; ++cb)
            Hs[(orow + reg) * 136 + cb * 16 + oc] = (_Float16)(ah[cb][reg] * d);
    }
    __syncthreads();
#pragma unroll
    for (int it = 0; it < 4; ++it) {
        int i = it * 256 + tid;          // 1024 chunks of 8 halfs
        int r = i >> 4, c = (i & 15) * 8;
        if (row0 + r < n)
            *(half8*)&hs[(size_t)(row0 + r) * DIM + c] = *(const half8*)&Hs[r * 136 + c];
    }
    // P: acc-image, 32 halfs/lane contiguous
    _Float16* pl = P + ((size_t)(blockIdx.x * 4 + w) * 64 + l) * 32;
#pragma unroll
    for (int c = 0; c < 4; ++c) {
        half8 o;
#pragma unroll
        for (int e = 0; e < 4; ++e) {
            o[e]     = (_Float16)ap[2 * c][e];
            o[4 + e] = (_Float16)ap[2 * c + 1][e];
        }
        *(half8*)&pl[c * 8] = o;
    }
}

// ---------------- mm2g: fused gather1 + GEMM2-half ----------------
// 16-lane-group gather (4/2/1-wide load ladder), frag-order LDS A-tile, MFMA,
// LDS-transpose epilogue. hs2 aliases P (block-private; P consumed before barrier).
__global__ __launch_bounds__(256, 2) void k_mm2g(
    const _Float16* __restrict__ hs, const int* __restrict__ cursor,
    const int* __restrict__ srcs, const float* __restrict__ b1,
    const _Float16* __restrict__ Wp2, const _Float16* __restrict__ P,
    _Float16* __restrict__ hs2, int n) {
    __shared__ _Float16 LS[64 * 136];  // Af = first 8192 halfs; reused as Hs after MFMA
    const int tid = threadIdx.x;
    const int w = tid >> 6, l = tid & 63;
    const int g = tid & 15, gid = tid >> 4;
    const int row0 = blockIdx.x * 64;

    // init acc from P (block-private; fully read before any barrier)
    f32x4 acc[8];
    const _Float16* pl = P + ((size_t)(blockIdx.x * 4 + w) * 64 + l) * 32;
#pragma unroll
    for (int c = 0; c < 4; ++c) {
        half8 pv = *(const half8*)&pl[c * 8];
#pragma unroll
        for (int e = 0; e < 4; ++e) {
            acc[2 * c][e]     = (float)pv[e];
            acc[2 * c + 1][e] = (float)pv[4 + e];
        }
    }

    // gather: 16 lanes per node (lane = feature chunk), 4 sweeps of 16 nodes
#pragma unroll
    for (int it = 0; it < 4; ++it) {
        int node = row0 + it * 16 + gid;
        half8 o = 0;
        if (node < n) {
            int rawc = cursor[node];
            int cnt = rawc > CAP ? CAP : rawc;
            const int* sl = &srcs[(size_t)node * CAP];
            half8 h = *(const half8*)&hs[(size_t)node * DIM + g * 8];
            float a[8];
#pragma unroll
            for (int e = 0; e < 8; ++e) a[e] = (float)h[e];
            for (int base = 0; base < cnt; base += 16) {
                int m = cnt - base;
                if (m > 16) m = 16;
                int sidb = (g < m) ? sl[base + g] : 0;
                int j = 0;
                for (; j + 4 <= m; j += 4) {
                    int s0 = __shfl(sidb, j, 16);
                    int s1 = __shfl(sidb, j + 1, 16);
                    int s2 = __shfl(sidb, j + 2, 16);
                    int s3 = __shfl(sidb, j + 3, 16);
                    half8 v0 = *(const half8*)&hs[(size_t)s0 * DIM + g * 8];
                    half8 v1 = *(const half8*)&hs[(size_t)s1 * DIM + g * 8];
                    half8 v2 = *(const half8*)&hs[(size_t)s2 * DIM + g * 8];
                    half8 v3 = *(const half8*)&hs[(size_t)s3 * DIM + g * 8];
#pragma unroll
                    for (int e = 0; e < 8; ++e)
                        a[e] += (float)v0[e] + (float)v1[e] + (float)v2[e] + (float)v3[e];
                }
                for (; j + 2 <= m; j += 2) {
                    int s0 = __shfl(sidb, j, 16);
                    int s1 = __shfl(sidb, j + 1, 16);
                    half8 v0 = *(const half8*)&hs[(size_t)s0 * DIM + g * 8];
                    half8 v1 = *(const half8*)&hs[(size_t)s1 * DIM + g * 8];
#pragma unroll
                    for (int e = 0; e < 8; ++e) a[e] += (float)v0[e] + (float)v1[e];
                }
                if (j < m) {
                    int s0 = __shfl(sidb, j, 16);
                    half8 v0 = *(const half8*)&hs[(size_t)s0 * DIM + g * 8];
#pragma unroll
                    for (int e = 0; e < 8; ++e) a[e] += (float)v0[e];
                }
            }
            float d = rsqrtf((float)rawc + 1.0f);
            const float4 bb0 = *(const float4*)&b1[g * 8];
            const float4 bb1 = *(const float4*)&b1[g * 8 + 4];
            o[0] = (_Float16)lrelu(fmaf(a[0], d, bb0.x));
            o[1] = (_Float16)lrelu(fmaf(a[1], d, bb0.y));
            o[2] = (_Float16)lrelu(fmaf(a[2], d, bb0.z));
            o[3] = (_Float16)lrelu(fmaf(a[3], d, bb0.w));
            o[4] = (_Float16)lrelu(fmaf(a[4], d, bb1.x));
            o[5] = (_Float16)lrelu(fmaf(a[5], d, bb1.y));
            o[6] = (_Float16)lrelu(fmaf(a[6], d, bb1.z));
            o[7] = (_Float16)lrelu(fmaf(a[7], d, bb1.w));
        }
        // A-frag write: frag = it*4 + (g>>2); lane-in-frag = (g&3)*16 + gid  (row m = gid)
        *(half8*)&LS[(((it * 4 + (g >> 2)) * 64) + (g & 3) * 16 + gid) * 8] = o;
    }
    __syncthreads();

#pragma unroll
    for (int kb = 0; kb < 4; ++kb) {
        half8 a = *(const half8*)&LS[((w * 4 + kb) * 64 + l) * 8];
#pragma unroll
        for (int cb = 0; cb < 8; ++cb) {
            half8 bf = *(const half8*)&Wp2[(((kb + 4) * 8 + cb) * 64 + l) * 8];  // W2 rows 128..255
            acc[cb] = __builtin_amdgcn_mfma_f32_16x16x32_f16(a, bf, acc[cb], 0, 0, 0);
        }
    }
    __syncthreads();  // all waves done reading Af before Hs overwrite
    const int orow = w * 16 + ((l >> 4) << 2);
    const int oc = l & 15;
#pragma unroll
    for (int reg = 0; reg < 4; ++reg) {
        int grow = row0 + orow + reg;
        float d = (grow < n) ? rsqrtf((float)cursor[grow] + 1.0f) : 0.f;
#pragma unroll
        for (int cb = 0; cb < 8; ++cb)
            LS[(orow + reg) * 136 + cb * 16 + oc] = (_Float16)(acc[cb][reg] * d);
    }
    __syncthreads();
#pragma unroll
    for (int it = 0; it < 4; ++it) {
        int i = it * 256 + tid;
        int r = i >> 4, c = (i & 15) * 8;
        if (row0 + r < n)
            *(half8*)&hs2[(size_t)(row0 + r) * DIM + c] = *(const half8*)&LS[r * 136 + c];
    }
}

// ---------------- gather2 + final projection (16-lane groups) ----------------
__global__ __launch_bounds__(256) void k_gather2(
    const _Float16* __restrict__ hs2, const int* __restrict__ cursor,
    const int* __restrict__ srcs, const float* __restrict__ b2,
    const float* __restrict__ wout, const float* __restrict__ bout,
    float* __restrict__ out, int n) {
    const int node = blockIdx.x * 16 + (threadIdx.x >> 4);
    const int g = threadIdx.x & 15;
    if (node >= n) return;
    int rawc = cursor[node];
    int cnt = rawc > CAP ? CAP : rawc;
    const int* sl = &srcs[(size_t)node * CAP];
    half8 h = *(const half8*)&hs2[(size_t)node * DIM + g * 8];
    float a[8];
#pragma unroll
    for (int e = 0; e < 8; ++e) a[e] = (float)h[e];
    for (int base = 0; base < cnt; base += 16) {
        int m = cnt - base;
        if (m > 16) m = 16;
        int sidb = (g < m) ? sl[base + g] : 0;
        int j = 0;
        for (; j + 4 <= m; j += 4) {
            int s0 = __shfl(sidb, j, 16);
            int s1 = __shfl(sidb, j + 1, 16);
            int s2 = __shfl(sidb, j + 2, 16);
            int s3 = __shfl(sidb, j + 3, 16);
            half8 v0 = *(const half8*)&hs2[(size_t)s0 * DIM + g * 8];
            half8 v1 = *(const half8*)&hs2[(size_t)s1 * DIM + g * 8];
            half8 v2 = *(const half8*)&hs2[(size_t)s2 * DIM + g * 8];
            half8 v3 = *(const half8*)&hs2[(size_t)s3 * DIM + g * 8];
#pragma unroll
            for (int e = 0; e < 8; ++e)
                a[e] += (float)v0[e] + (float)v1[e] + (float)v2[e] + (float)v3[e];
        }
        for (; j + 2 <= m; j += 2) {
            int s0 = __shfl(sidb, j, 16);
            int s1 = __shfl(sidb, j + 1, 16);
            half8 v0 = *(const half8*)&hs2[(size_t)s0 * DIM + g * 8];
            half8 v1 = *(const half8*)&hs2[(size_t)s1 * DIM + g * 8];
#pragma unroll
            for (int e = 0; e < 8; ++e) a[e] += (float)v0[e] + (float)v1[e];
        }
        if (j < m) {
            int s0 = __shfl(sidb, j, 16);
            half8 v0 = *(const half8*)&hs2[(size_t)s0 * DIM + g * 8];
#pragma unroll
            for (int e = 0; e < 8; ++e) a[e] += (float)v0[e];
        }
    }
    float d = rsqrtf((float)rawc + 1.0f);
    const float4 bb0 = *(const float4*)&b2[g * 8];
    const float4 bb1 = *(const float4*)&b2[g * 8 + 4];
    const float4 wv0 = *(const float4*)&wout[g * 8];
    const float4 wv1 = *(const float4*)&wout[g * 8 + 4];
    float s = lrelu(fmaf(a[0], d, bb0.x)) * wv0.x + lrelu(fmaf(a[1], d, bb0.y)) * wv0.y +
              lrelu(fmaf(a[2], d, bb0.z)) * wv0.z + lrelu(fmaf(a[3], d, bb0.w)) * wv0.w +
              lrelu(fmaf(a[4], d, bb1.x)) * wv1.x + lrelu(fmaf(a[5], d, bb1.y)) * wv1.y +
              lrelu(fmaf(a[6], d, bb1.z)) * wv1.z + lrelu(fmaf(a[7], d, bb1.w)) * wv1.w;
#pragma unroll
    for (int off = 8; off > 0; off >>= 1) s += __shfl_down(s, off, 16);
    if (g == 0) out[node] = s + bout[0];
}

extern "C" void kernel_launch(void* const* d_in, const int* in_sizes, int n_in,
                              void* d_out, int out_size, void* d_ws, size_t ws_size,
                              hipStream_t stream) {
    const float* x    = (const float*)d_in[0];
    const int*   ei   = (const int*)d_in[1];
    const float* W1   = (const float*)d_in[2];
    const float* b1   = (const float*)d_in[3];
    const float* W2   = (const float*)d_in[4];
    const float* b2   = (const float*)d_in[5];
    const float* Wout = (const float*)d_in[6];
    const float* bout = (const float*)d_in[7];
    float* out = (float*)d_out;

    const int N = in_sizes[0] / DIM;
    const int E = in_sizes[1] / 2;
    const int* src = ei;      // edge_index[0]
    const int* dst = ei + E;  // edge_index[1]

    const int gb = (N + 63) / 64;
    const long long nx = (long long)N * DIM;

    // workspace
    size_t Na = ((size_t)N + 63) & ~(size_t)63;
    int* cursor   = (int*)d_ws;                          // Na
    int* srcs     = cursor + Na;                         // N*CAP
    _Float16* Wp1 = (_Float16*)(srcs + (size_t)N * CAP); // 128*128
    _Float16* Wp2 = Wp1 + 128 * 128;                     // 256*128
    _Float16* hsb = Wp2 + 256 * 128;                     // N*128 (hs)
    _Float16* Pb  = hsb + nx;                            // gb*8192 (P -> hs2)

    const int eb = (E + 255) / 256;

    hipMemsetAsync(cursor, 0, (size_t)N * sizeof(int), stream);
    k_prep<<<eb + 192, 256, 0, stream>>>(src, dst, cursor, srcs, E, eb, W1, Wp1, W2, Wp2);
    k_mm1<<<gb, 256, 0, stream>>>(x, Wp1, Wp2, cursor, hsb, Pb, N);
    k_mm2g<<<gb, 256, 0, stream>>>(hsb, cursor, srcs, b1, Wp2, Pb, Pb, N);
    k_gather2<<<(N + 15) / 16, 256, 0, stream>>>(Pb, cursor, srcs, b2, Wout, bout, out, N);
}